// Round 9
// baseline (63.025 us; speedup 1.0000x reference)
//
#include <hip/hip_runtime.h>

#define L_IN   2048
#define C_IN   512
#define L_OUT  2045
#define XT_PAD 21
#define CS     520    // xtile row stride (elems)
#define DS2    1218   // out2 m2-stride (dwords)
#define AS2    38     // out2 a-stride (dwords)

typedef short short8 __attribute__((ext_vector_type(8)));
typedef float float4v __attribute__((ext_vector_type(4)));

__device__ __forceinline__ unsigned short bf16r(float f) {
    unsigned u = __float_as_uint(f);
    unsigned r = (u + 0x7FFFu + ((u >> 16) & 1u)) >> 16;
    return (unsigned short)r;
}

// ---------------- kernel 1: build W21/W43 in MFMA fragment layout (verified R3/R5/R6) ----
__global__ __launch_bounds__(256)
void build_wf(const float* __restrict__ tw, unsigned short* __restrict__ W21f,
              unsigned short* __restrict__ W43f) {
    int id = blockIdx.x * 256 + threadIdx.x;
    if (id < 65536) {
        int p = id & 7, lane = (id >> 3) & 63, oh = (id >> 9) & 1, g = id >> 10;
        int a = oh * 16 + (lane & 15);
        int e = ((lane >> 4) & 3) * 8 + p;
        int r2 = a >> 2, d2 = a & 3, c2 = e >> 2, c1 = e & 3;
        float v = tw[8192 + ((g * 4 + d2) * 8 + r2) * 8 + c2]
                * tw[(g * 8 + c2) * 16 + d2 * 4 + c1];
        W21f[id] = bf16r(v);
    } else if (id < 98304) {
        int id2 = id - 65536;
        int p = id2 & 7, lane = (id2 >> 3) & 63, kh = (id2 >> 9) & 1, s = id2 >> 10;
        int u = lane & 15;
        int w = kh * 32 + ((lane >> 4) & 3) * 8 + p;
        int r4 = u >> 1, hi = u & 1, d4 = hi * 32 + s, p2 = w >> 3, c3 = w & 7;
        float v = 0.f;
        #pragma unroll
        for (int lo = 0; lo < 2; ++lo)
            v += tw[32768 + (d4 * 8 + r4) * 16 + (2 * p2 + lo)]
               * tw[24576 + ((p2 * 32 + s) * 4 + (2 * lo + hi)) * 8 + c3];
        W43f[id2] = bf16r(v);
    }
}

// ---------------- kernel 2: fused, 2 l-tiles per block, pipelined x-staging --------------
__global__ __launch_bounds__(512)
void debut_fused2(const unsigned short* __restrict__ W21f,
                  const unsigned short* __restrict__ W43f,
                  const float* __restrict__ x,
                  const float* __restrict__ bias, float* __restrict__ out) {
    __shared__ unsigned short xtile[20 * CS];   // 20800 B
    __shared__ unsigned int   out2[9736];       // 38944 B  (total 59744 -> 2 blocks/CU)

    const int bid = blockIdx.x;                 // 1024
    const int swz = (bid & 7) * 128 + (bid >> 3);
    const int ltp = swz & 63, b = swz >> 6;     // l-pair tile (32 l), batch
    const int t = threadIdx.x;
    const int lane = t & 63, wv = t >> 6;
    const int lr = lane & 15, lh = lane >> 4;
    const int lq = t & 3, ccq = t >> 2;

    const float* xb = x + (size_t)b * C_IN * L_IN;

    // stage-B A-operands (L2-resident), amortized over both tiles
    short8 wa[4][2];
    #pragma unroll
    for (int si = 0; si < 4; ++si) {
        int s = wv * 4 + si;
        wa[si][0] = *(const short8*)(W43f + ((size_t)(s * 2 + 0) * 64 + lane) * 8);
        wa[si][1] = *(const short8*)(W43f + ((size_t)(s * 2 + 1) * 64 + lane) * 8);
    }

#define XLOAD(dst, L0)                                                                   \
    do {                                                                                 \
        _Pragma("unroll")                                                                \
        for (int pass = 0; pass < 4; ++pass)                                             \
            dst[pass] = *(const float4*)(xb + (size_t)(pass * 128 + ccq) * L_IN + (L0) + lq * 4); \
        int lx = (L0) + 16; if (lx > L_IN - 4) lx = L_IN - 4;                            \
        dst[4] = *(const float4*)(xb + (size_t)t * L_IN + lx);                           \
    } while (0)

#define XWRITE(src)                                                                      \
    do {                                                                                 \
        _Pragma("unroll")                                                                \
        for (int pass = 0; pass < 4; ++pass) {                                           \
            int base = (lq * 4) * CS + (pass * 128 + ccq);                               \
            xtile[base         ] = bf16r(src[pass].x);                                   \
            xtile[base + CS    ] = bf16r(src[pass].y);                                   \
            xtile[base + 2 * CS] = bf16r(src[pass].z);                                   \
            xtile[base + 3 * CS] = bf16r(src[pass].w);                                   \
        }                                                                                \
        int base = 16 * CS + t;                                                          \
        xtile[base         ] = bf16r(src[4].x);                                          \
        xtile[base + CS    ] = bf16r(src[4].y);                                          \
        xtile[base + 2 * CS] = bf16r(src[4].z);                                          \
        xtile[base + 3 * CS] = bf16r(src[4].w);                                          \
    } while (0)

#define STAGE_A(P)                                                                       \
    do {                                                                                 \
        const int koff = 2 * (P) + (wv >> 2);                                            \
        const unsigned short* xrow = &xtile[(lr + koff) * CS + lh * 8];                  \
        _Pragma("unroll")                                                                \
        for (int gi = 0; gi < 4; ++gi) {                                                 \
            const int gp = wv * 4 + gi;                                                  \
            const int g  = (P) * 32 + gp;                                                \
            short8 vfrag = *(const short8*)(xrow + (gp & 15) * 32);                      \
            _Pragma("unroll")                                                            \
            for (int oh = 0; oh < 2; ++oh) {                                             \
                short8 wfrag = *(const short8*)(W21f + ((size_t)(g * 2 + oh) * 64 + lane) * 8); \
                float4v acc = {};                                                        \
                acc = __builtin_amdgcn_mfma_f32_16x16x32_bf16(vfrag, wfrag, acc, 0, 0, 0); \
                const int a = oh * 16 + lr;                                              \
                unsigned d0 = (unsigned)bf16r(acc[0]) | ((unsigned)bf16r(acc[1]) << 16); \
                unsigned d1 = (unsigned)bf16r(acc[2]) | ((unsigned)bf16r(acc[3]) << 16); \
                out2[(lh * 2 + 0) * DS2 + a * AS2 + gp] = d0;                            \
                out2[(lh * 2 + 1) * DS2 + a * AS2 + gp] = d1;                            \
            }                                                                            \
        }                                                                                \
    } while (0)

#define STAGE_B(P, accB)                                                                 \
    do {                                                                                 \
        _Pragma("unroll")                                                                \
        for (int si = 0; si < 4; ++si) {                                                 \
            const int s = wv * 4 + si;                                                   \
            const int rb = (lr >> 1) * DS2 + s * AS2 + lh * 8;                           \
            uint2 q0 = *(const uint2*)&out2[rb + 0];                                     \
            uint2 q1 = *(const uint2*)&out2[rb + 2];                                     \
            uint2 q2 = *(const uint2*)&out2[rb + 4];                                     \
            uint2 q3 = *(const uint2*)&out2[rb + 6];                                     \
            unsigned w0, w1, w2, w3;                                                     \
            if (lr & 1) {                                                                \
                w0 = (q0.x >> 16) | (q0.y & 0xffff0000u);                                \
                w1 = (q1.x >> 16) | (q1.y & 0xffff0000u);                                \
                w2 = (q2.x >> 16) | (q2.y & 0xffff0000u);                                \
                w3 = (q3.x >> 16) | (q3.y & 0xffff0000u);                                \
            } else {                                                                     \
                w0 = (q0.x & 0xffffu) | (q0.y << 16);                                    \
                w1 = (q1.x & 0xffffu) | (q1.y << 16);                                    \
                w2 = (q2.x & 0xffffu) | (q2.y << 16);                                    \
                w3 = (q3.x & 0xffffu) | (q3.y << 16);                                    \
            }                                                                            \
            uint4 uw{w0, w1, w2, w3};                                                    \
            short8 bb = *reinterpret_cast<short8*>(&uw);                                 \
            accB[si] = __builtin_amdgcn_mfma_f32_16x16x32_bf16(wa[si][P], bb, accB[si], 0, 0, 0); \
        }                                                                                \
    } while (0)

#define STORE(L0, accB)                                                                  \
    do {                                                                                 \
        const int lpos = (L0) + lr;                                                      \
        if (lpos < L_OUT) {                                                              \
            _Pragma("unroll")                                                            \
            for (int si = 0; si < 4; ++si) {                                             \
                const int s = wv * 4 + si;                                               \
                _Pragma("unroll")                                                        \
                for (int i = 0; i < 4; ++i) {                                            \
                    int o4 = s + 32 * (lh * 4 + i);                                      \
                    out[((size_t)(b * 512 + o4)) * L_OUT + lpos] = accB[si][i] + bias[o4]; \
                }                                                                        \
            }                                                                            \
        }                                                                                \
    } while (0)

    const int l0a = ltp * 32;
    const int l0b = l0a + 16;

    // ---- tile 0 staging ----
    float4 xv[5];
    XLOAD(xv, l0a);
    XWRITE(xv);
    __syncthreads();

    // ---- tile 0 compute ----
    {
        float4v accB[4] = {};
        STAGE_A(0);
        __syncthreads();
        STAGE_B(0, accB);
        float4 yv[5];
        XLOAD(yv, l0b);            // issue tile-1 loads; in flight across phases
        __syncthreads();
        STAGE_A(1);
        __syncthreads();
        STAGE_B(1, accB);
        STORE(l0a, accB);
        XWRITE(yv);                // xtile free after STAGE_A(1) barrier
        __syncthreads();
    }

    // ---- tile 1 compute ----
    {
        float4v accB[4] = {};
        STAGE_A(0);
        __syncthreads();
        STAGE_B(0, accB);
        __syncthreads();
        STAGE_A(1);
        __syncthreads();
        STAGE_B(1, accB);
        STORE(l0b, accB);
    }

#undef XLOAD
#undef XWRITE
#undef STAGE_A
#undef STAGE_B
#undef STORE
}

// ---------------- fallback (round-1 kernel, used if ws too small) ----------------
__global__ __launch_bounds__(256)
void debut_fused_kernel(const float* __restrict__ x,
                        const float* __restrict__ tw,
                        const float* __restrict__ bias,
                        float* __restrict__ out)
{
    __shared__ float xt[C_IN * XT_PAD];
    __shared__ float bufA[2048];
    __shared__ float bufB[2048];
    const int tile = blockIdx.x, b = blockIdx.y;
    const int l0 = tile * 16;
    const int tid = threadIdx.x;
    const float* xb = x + (size_t)b * C_IN * L_IN;
    for (int idx = tid; idx < C_IN * 19; idx += 256) {
        int c = idx / 19, ll = idx - c * 19, l = l0 + ll;
        xt[c * XT_PAD + ll] = (l < L_IN) ? xb[c * L_IN + l] : 0.0f;
    }
    __syncthreads();
    const float* t1 = tw; const float* t2 = tw + 8192;
    const float* t3 = tw + 24576; const float* t4 = tw + 32768;
    for (int rr = 0; rr < 16; ++rr) {
        const int l = l0 + rr;
        if (l >= L_OUT) break;
        #pragma unroll
        for (int i = 0; i < 8; ++i) {
            int o = tid + 256 * i, gb = o >> 2, k = gb >> 7, cb = (gb & 127) << 2;
            const float4 tq = *reinterpret_cast<const float4*>(t1 + o * 4);
            const float* xp = &xt[cb * XT_PAD + rr + k];
            bufA[o] = tq.x * xp[0] + tq.y * xp[XT_PAD] + tq.z * xp[2 * XT_PAD] + tq.w * xp[3 * XT_PAD];
        }
        __syncthreads();
        #pragma unroll
        for (int i = 0; i < 8; ++i) {
            int o = tid + 256 * i, gb = o >> 5, r = (o >> 2) & 7, d = o & 3;
            const float* tp = t2 + (((gb << 2) + d) * 8 + r) * 8;
            const float* ip = &bufA[(gb << 5) + d];
            float acc = 0.0f;
            #pragma unroll
            for (int c = 0; c < 8; ++c) acc += tp[c] * ip[c << 2];
            bufB[o] = acc;
        }
        __syncthreads();
        #pragma unroll
        for (int i = 0; i < 4; ++i) {
            int o = tid + 256 * i, gb = o >> 7, r = (o >> 5) & 3, d = o & 31;
            const float* tp = t3 + (((gb << 5) + d) * 4 + r) * 8;
            const float* ip = &bufB[(gb << 8) + d];
            float acc = 0.0f;
            #pragma unroll
            for (int c = 0; c < 8; ++c) acc += tp[c] * ip[c << 5];
            bufA[o] = acc;
        }
        __syncthreads();
        #pragma unroll
        for (int i = 0; i < 2; ++i) {
            int o = tid + 256 * i, r = o >> 6, d = o & 63;
            const float* tp = t4 + ((d << 3) + r) * 16;
            float acc = 0.0f;
            #pragma unroll
            for (int c = 0; c < 16; ++c) acc += tp[c] * bufA[(c << 6) + d];
            out[((size_t)(b * 512 + o)) * L_OUT + l] = acc + bias[o];
        }
        __syncthreads();
    }
}

extern "C" void kernel_launch(void* const* d_in, const int* in_sizes, int n_in,
                              void* d_out, int out_size, void* d_ws, size_t ws_size,
                              hipStream_t stream) {
    const float* x    = (const float*)d_in[0];
    const float* tw   = (const float*)d_in[1];
    const float* bias = (const float*)d_in[2];
    float* out = (float*)d_out;

    const size_t W21_B = 65536 * 2;      // 128 KB
    const size_t W43_B = 32768 * 2;      // 64 KB

    if (ws_size < W21_B + W43_B) {
        dim3 grid(128, 16);
        debut_fused_kernel<<<grid, dim3(256), 0, stream>>>(x, tw, bias, out);
        return;
    }

    unsigned short* W21f = (unsigned short*)d_ws;
    unsigned short* W43f = (unsigned short*)((char*)d_ws + W21_B);

    build_wf<<<dim3(384), dim3(256), 0, stream>>>(tw, W21f, W43f);
    debut_fused2<<<dim3(1024), dim3(512), 0, stream>>>(W21f, W43f, x, bias, out);
}

// Round 10
// 47.769 us; speedup vs baseline: 1.3194x; 1.3194x over previous
//
#include <hip/hip_runtime.h>

#define L_IN   2048
#define C_IN   512
#define L_OUT  2045
#define XT_PAD 21
#define CS     520    // xtile row stride (elems)
#define MS3    1058   // out2 m2-stride (dwords)  [m2][gp][a] layout
#define GS3    33     // out2 gp-stride (dwords)

typedef short short8 __attribute__((ext_vector_type(8)));
typedef float float4v __attribute__((ext_vector_type(4)));

__device__ __forceinline__ unsigned short bf16r(float f) {
    unsigned u = __float_as_uint(f);
    unsigned r = (u + 0x7FFFu + ((u >> 16) & 1u)) >> 16;
    return (unsigned short)r;
}

// ---------------- kernel 1: build W21/W43 in MFMA fragment layout (verified R3/R5/R6) ----
__global__ __launch_bounds__(256)
void build_wf(const float* __restrict__ tw, unsigned short* __restrict__ W21f,
              unsigned short* __restrict__ W43f) {
    int id = blockIdx.x * 256 + threadIdx.x;
    if (id < 65536) {
        int p = id & 7, lane = (id >> 3) & 63, oh = (id >> 9) & 1, g = id >> 10;
        int a = oh * 16 + (lane & 15);
        int e = ((lane >> 4) & 3) * 8 + p;
        int r2 = a >> 2, d2 = a & 3, c2 = e >> 2, c1 = e & 3;
        float v = tw[8192 + ((g * 4 + d2) * 8 + r2) * 8 + c2]
                * tw[(g * 8 + c2) * 16 + d2 * 4 + c1];
        W21f[id] = bf16r(v);
    } else if (id < 98304) {
        int id2 = id - 65536;
        int p = id2 & 7, lane = (id2 >> 3) & 63, kh = (id2 >> 9) & 1, s = id2 >> 10;
        int u = lane & 15;
        int w = kh * 32 + ((lane >> 4) & 3) * 8 + p;
        int r4 = u >> 1, hi = u & 1, d4 = hi * 32 + s, p2 = w >> 3, c3 = w & 7;
        float v = 0.f;
        #pragma unroll
        for (int lo = 0; lo < 2; ++lo)
            v += tw[32768 + (d4 * 8 + r4) * 16 + (2 * p2 + lo)]
               * tw[24576 + ((p2 * 32 + s) * 4 + (2 * lo + hi)) * 8 + c3];
        W43f[id2] = bf16r(v);
    }
}

// ---------------- kernel 2: fused single-tile (R7 structure), 3 blocks/CU ----------------
// xtile[l][c] bf16, 19 rows. out2 dwords [m2][gp][a]: dw = m2*MS3 + gp*GS3 + a,
// each dw = bf16 pair (m=2*m2, m=2*m2+1). Phase p: g = p*32 + gp.
__global__ __launch_bounds__(512, 6)
void debut_fused_mfma(const unsigned short* __restrict__ W21f,
                      const unsigned short* __restrict__ W43f,
                      const float* __restrict__ x,
                      const float* __restrict__ bias, float* __restrict__ out) {
    __shared__ unsigned short xtile[19 * CS];   // 19760 B
    __shared__ unsigned int   out2[8464];       // 33856 B   (total 53616 -> 3 blocks/CU)

    // XCD-aware bijective swizzle (2048 blocks, 8 XCDs, 256 each)
    const int bid = blockIdx.x;
    const int swz = (bid & 7) * 256 + (bid >> 3);
    const int lt = swz & 127, b = swz >> 7;
    const int l0 = lt * 16;
    const int t = threadIdx.x;
    const int lane = t & 63, wv = t >> 6;        // 8 waves
    const int lr = lane & 15, lh = lane >> 4;

    const float* xb = x + (size_t)b * C_IN * L_IN;

    // ---- stage x: x[b, :, l0..l0+18] -> xtile (coalesced 64B-per-row reads) ----
    {
        const int lq = t & 3;
        #pragma unroll
        for (int pass = 0; pass < 4; ++pass) {
            int cc = pass * 128 + (t >> 2);
            float4 v = *reinterpret_cast<const float4*>(xb + (size_t)cc * L_IN + l0 + lq * 4);
            int base = (lq * 4) * CS + cc;
            xtile[base         ] = bf16r(v.x);
            xtile[base + CS    ] = bf16r(v.y);
            xtile[base + 2 * CS] = bf16r(v.z);
            xtile[base + 3 * CS] = bf16r(v.w);
        }
        // tail rows 16..18 (clamped near signal end; OOB rows feed masked outputs only)
        int cc = t;
        int lx = l0 + 16; if (lx > L_IN - 4) lx = L_IN - 4;
        float4 v = *reinterpret_cast<const float4*>(xb + (size_t)cc * L_IN + lx);
        int base = 16 * CS + cc;
        xtile[base         ] = bf16r(v.x);
        xtile[base + CS    ] = bf16r(v.y);
        xtile[base + 2 * CS] = bf16r(v.z);
    }

    // hoist stage-B A-operand loads (L2-resident, independent of LDS)
    short8 wa[4][2];
    #pragma unroll
    for (int si = 0; si < 4; ++si) {
        int s = wv * 4 + si;
        wa[si][0] = *(const short8*)(W43f + ((size_t)(s * 2 + 0) * 64 + lane) * 8);
        wa[si][1] = *(const short8*)(W43f + ((size_t)(s * 2 + 1) * 64 + lane) * 8);
    }

    __syncthreads();

    float4v accB[4] = {};

    #pragma unroll
    for (int p = 0; p < 2; ++p) {
        // ---- stage A: wave wv handles gp = wv*4 .. +3 (g = p*32 + gp) ----
        const int koff = 2 * p + (wv >> 2);
        const unsigned short* xrow = &xtile[(lr + koff) * CS + lh * 8];

        #pragma unroll
        for (int gi = 0; gi < 4; ++gi) {
            const int gp = wv * 4 + gi;
            const int g  = p * 32 + gp;
            short8 vfrag = *(const short8*)(xrow + (gp & 15) * 32);
            #pragma unroll
            for (int oh = 0; oh < 2; ++oh) {
                short8 wfrag = *(const short8*)(W21f + ((size_t)(g * 2 + oh) * 64 + lane) * 8);
                float4v acc = {};
                acc = __builtin_amdgcn_mfma_f32_16x16x32_bf16(vfrag, wfrag, acc, 0, 0, 0);
                // lane: a = oh*16+lr (D col), m = lh*4+i (D row) -> 2 packed b32 writes
                const int a = oh * 16 + lr;
                unsigned d0 = (unsigned)bf16r(acc[0]) | ((unsigned)bf16r(acc[1]) << 16);
                unsigned d1 = (unsigned)bf16r(acc[2]) | ((unsigned)bf16r(acc[3]) << 16);
                out2[(lh * 2 + 0) * MS3 + gp * GS3 + a] = d0;
                out2[(lh * 2 + 1) * MS3 + gp * GS3 + a] = d1;
            }
        }
        __syncthreads();

        // ---- stage B: wave wv accumulates s = wv*4 .. +3 over this phase's 32 g ----
        #pragma unroll
        for (int si = 0; si < 4; ++si) {
            const int s = wv * 4 + si;
            const int rb = (lr >> 1) * MS3 + s + (lh * 8) * GS3;
            unsigned d0 = out2[rb + 0 * GS3];
            unsigned d1 = out2[rb + 1 * GS3];
            unsigned d2 = out2[rb + 2 * GS3];
            unsigned d3 = out2[rb + 3 * GS3];
            unsigned d4 = out2[rb + 4 * GS3];
            unsigned d5 = out2[rb + 5 * GS3];
            unsigned d6 = out2[rb + 6 * GS3];
            unsigned d7 = out2[rb + 7 * GS3];
            unsigned w0, w1, w2, w3;
            if (lr & 1) {
                w0 = (d0 >> 16) | (d1 & 0xffff0000u);
                w1 = (d2 >> 16) | (d3 & 0xffff0000u);
                w2 = (d4 >> 16) | (d5 & 0xffff0000u);
                w3 = (d6 >> 16) | (d7 & 0xffff0000u);
            } else {
                w0 = (d0 & 0xffffu) | (d1 << 16);
                w1 = (d2 & 0xffffu) | (d3 << 16);
                w2 = (d4 & 0xffffu) | (d5 << 16);
                w3 = (d6 & 0xffffu) | (d7 << 16);
            }
            uint4 uw{w0, w1, w2, w3};
            short8 bb = *reinterpret_cast<short8*>(&uw);
            accB[si] = __builtin_amdgcn_mfma_f32_16x16x32_bf16(wa[si][p], bb, accB[si], 0, 0, 0);
        }
        if (p == 0) __syncthreads();   // protect out2 before phase-1 overwrite
    }

    // ---- store ----
    const int lpos = l0 + lr;
    if (lpos < L_OUT) {
        #pragma unroll
        for (int si = 0; si < 4; ++si) {
            const int s = wv * 4 + si;
            #pragma unroll
            for (int i = 0; i < 4; ++i) {
                int o4 = s + 32 * (lh * 4 + i);
                out[((size_t)(b * 512 + o4)) * L_OUT + lpos] = accB[si][i] + bias[o4];
            }
        }
    }
}

// ---------------- fallback (round-1 kernel, used if ws too small) ----------------
__global__ __launch_bounds__(256)
void debut_fused_kernel(const float* __restrict__ x,
                        const float* __restrict__ tw,
                        const float* __restrict__ bias,
                        float* __restrict__ out)
{
    __shared__ float xt[C_IN * XT_PAD];
    __shared__ float bufA[2048];
    __shared__ float bufB[2048];
    const int tile = blockIdx.x, b = blockIdx.y;
    const int l0 = tile * 16;
    const int tid = threadIdx.x;
    const float* xb = x + (size_t)b * C_IN * L_IN;
    for (int idx = tid; idx < C_IN * 19; idx += 256) {
        int c = idx / 19, ll = idx - c * 19, l = l0 + ll;
        xt[c * XT_PAD + ll] = (l < L_IN) ? xb[c * L_IN + l] : 0.0f;
    }
    __syncthreads();
    const float* t1 = tw; const float* t2 = tw + 8192;
    const float* t3 = tw + 24576; const float* t4 = tw + 32768;
    for (int rr = 0; rr < 16; ++rr) {
        const int l = l0 + rr;
        if (l >= L_OUT) break;
        #pragma unroll
        for (int i = 0; i < 8; ++i) {
            int o = tid + 256 * i, gb = o >> 2, k = gb >> 7, cb = (gb & 127) << 2;
            const float4 tq = *reinterpret_cast<const float4*>(t1 + o * 4);
            const float* xp = &xt[cb * XT_PAD + rr + k];
            bufA[o] = tq.x * xp[0] + tq.y * xp[XT_PAD] + tq.z * xp[2 * XT_PAD] + tq.w * xp[3 * XT_PAD];
        }
        __syncthreads();
        #pragma unroll
        for (int i = 0; i < 8; ++i) {
            int o = tid + 256 * i, gb = o >> 5, r = (o >> 2) & 7, d = o & 3;
            const float* tp = t2 + (((gb << 2) + d) * 8 + r) * 8;
            const float* ip = &bufA[(gb << 5) + d];
            float acc = 0.0f;
            #pragma unroll
            for (int c = 0; c < 8; ++c) acc += tp[c] * ip[c << 2];
            bufB[o] = acc;
        }
        __syncthreads();
        #pragma unroll
        for (int i = 0; i < 4; ++i) {
            int o = tid + 256 * i, gb = o >> 7, r = (o >> 5) & 3, d = o & 31;
            const float* tp = t3 + (((gb << 5) + d) * 4 + r) * 8;
            const float* ip = &bufB[(gb << 8) + d];
            float acc = 0.0f;
            #pragma unroll
            for (int c = 0; c < 8; ++c) acc += tp[c] * ip[c << 5];
            bufA[o] = acc;
        }
        __syncthreads();
        #pragma unroll
        for (int i = 0; i < 2; ++i) {
            int o = tid + 256 * i, r = o >> 6, d = o & 63;
            const float* tp = t4 + ((d << 3) + r) * 16;
            float acc = 0.0f;
            #pragma unroll
            for (int c = 0; c < 16; ++c) acc += tp[c] * bufA[(c << 6) + d];
            out[((size_t)(b * 512 + o)) * L_OUT + l] = acc + bias[o];
        }
        __syncthreads();
    }
}

extern "C" void kernel_launch(void* const* d_in, const int* in_sizes, int n_in,
                              void* d_out, int out_size, void* d_ws, size_t ws_size,
                              hipStream_t stream) {
    const float* x    = (const float*)d_in[0];
    const float* tw   = (const float*)d_in[1];
    const float* bias = (const float*)d_in[2];
    float* out = (float*)d_out;

    const size_t W21_B = 65536 * 2;      // 128 KB
    const size_t W43_B = 32768 * 2;      // 64 KB

    if (ws_size < W21_B + W43_B) {
        dim3 grid(128, 16);
        debut_fused_kernel<<<grid, dim3(256), 0, stream>>>(x, tw, bias, out);
        return;
    }

    unsigned short* W21f = (unsigned short*)d_ws;
    unsigned short* W43f = (unsigned short*)((char*)d_ws + W21_B);

    build_wf<<<dim3(384), dim3(256), 0, stream>>>(tw, W21f, W43f);
    debut_fused_mfma<<<dim3(2048), dim3(512), 0, stream>>>(W21f, W43f, x, bias, out);
}

// Round 11
// 46.184 us; speedup vs baseline: 1.3646x; 1.0343x over previous
//
#include <hip/hip_runtime.h>

#define L_IN   2048
#define C_IN   512
#define L_OUT  2045
#define XT_PAD 21
#define CS     520    // xtile row stride (elems)
#define GP2S   524    // out2 g-pair stride (dwords): 32a*16m=512 + 12 pad; 524%32=12, 524%4=0

typedef short short8 __attribute__((ext_vector_type(8)));
typedef float float4v __attribute__((ext_vector_type(4)));

__device__ __forceinline__ unsigned short bf16r(float f) {
    unsigned u = __float_as_uint(f);
    unsigned r = (u + 0x7FFFu + ((u >> 16) & 1u)) >> 16;
    return (unsigned short)r;
}

__device__ __forceinline__ unsigned bf16pk(float lo, float hi) {
    return (unsigned)bf16r(lo) | ((unsigned)bf16r(hi) << 16);
}

// ---------------- kernel 1: build W21/W43 in MFMA fragment layout (verified R3/R5/R6) ----
__global__ __launch_bounds__(256)
void build_wf(const float* __restrict__ tw, unsigned short* __restrict__ W21f,
              unsigned short* __restrict__ W43f) {
    int id = blockIdx.x * 256 + threadIdx.x;
    if (id < 65536) {
        int p = id & 7, lane = (id >> 3) & 63, oh = (id >> 9) & 1, g = id >> 10;
        int a = oh * 16 + (lane & 15);
        int e = ((lane >> 4) & 3) * 8 + p;
        int r2 = a >> 2, d2 = a & 3, c2 = e >> 2, c1 = e & 3;
        float v = tw[8192 + ((g * 4 + d2) * 8 + r2) * 8 + c2]
                * tw[(g * 8 + c2) * 16 + d2 * 4 + c1];
        W21f[id] = bf16r(v);
    } else if (id < 98304) {
        int id2 = id - 65536;
        int p = id2 & 7, lane = (id2 >> 3) & 63, kh = (id2 >> 9) & 1, s = id2 >> 10;
        int u = lane & 15;
        int w = kh * 32 + ((lane >> 4) & 3) * 8 + p;
        int r4 = u >> 1, hi = u & 1, d4 = hi * 32 + s, p2 = w >> 3, c3 = w & 7;
        float v = 0.f;
        #pragma unroll
        for (int lo = 0; lo < 2; ++lo)
            v += tw[32768 + (d4 * 8 + r4) * 16 + (2 * p2 + lo)]
               * tw[24576 + ((p2 * 32 + s) * 4 + (2 * lo + hi)) * 8 + c3];
        W43f[id2] = bf16r(v);
    }
}

// ---------------- kernel 2: fused two-stage block MFMA, g-pair dword exchange ------------
// xtile[l][c] bf16, 19 rows (verified R10).
// out2 dword dw(gp2, a, m) = gp2*GP2S + a*16 + m; content = (bf16 g=2*gp2, bf16 g=2*gp2+1)
//   at (a, m). Stage-A writes: b128 (4 m), zero-conflict. Stage-B reads: b32, 2-way.
// Phase p: local g = 0..31 (global g = p*32 + gl). accB accumulates across phases.
__global__ __launch_bounds__(512, 6)
void debut_fused_mfma(const unsigned short* __restrict__ W21f,
                      const unsigned short* __restrict__ W43f,
                      const float* __restrict__ x,
                      const float* __restrict__ bias, float* __restrict__ out) {
    __shared__ unsigned short xtile[19 * CS];   // 19760 B
    __shared__ unsigned int   out2[16 * GP2S];  // 33536 B   (total 53296 -> 3 blocks/CU)

    // XCD-aware bijective swizzle (2048 blocks, 8 XCDs, 256 each)
    const int bid = blockIdx.x;
    const int swz = (bid & 7) * 256 + (bid >> 3);
    const int lt = swz & 127, b = swz >> 7;
    const int l0 = lt * 16;
    const int t = threadIdx.x;
    const int lane = t & 63, wv = t >> 6;        // 8 waves
    const int lr = lane & 15, lh = lane >> 4;

    const float* xb = x + (size_t)b * C_IN * L_IN;

    // ---- stage x: x[b, :, l0..l0+18] -> xtile (verified R10) ----
    {
        const int lq = t & 3;
        #pragma unroll
        for (int pass = 0; pass < 4; ++pass) {
            int cc = pass * 128 + (t >> 2);
            float4 v = *reinterpret_cast<const float4*>(xb + (size_t)cc * L_IN + l0 + lq * 4);
            int base = (lq * 4) * CS + cc;
            xtile[base         ] = bf16r(v.x);
            xtile[base + CS    ] = bf16r(v.y);
            xtile[base + 2 * CS] = bf16r(v.z);
            xtile[base + 3 * CS] = bf16r(v.w);
        }
        int cc = t;
        int lx = l0 + 16; if (lx > L_IN - 4) lx = L_IN - 4;
        float4 v = *reinterpret_cast<const float4*>(xb + (size_t)cc * L_IN + lx);
        int base = 16 * CS + cc;
        xtile[base         ] = bf16r(v.x);
        xtile[base + CS    ] = bf16r(v.y);
        xtile[base + 2 * CS] = bf16r(v.z);
    }

    // hoist stage-B A-operand loads (L2-resident, independent of LDS)
    short8 wa[4][2];
    #pragma unroll
    for (int si = 0; si < 4; ++si) {
        int s = wv * 4 + si;
        wa[si][0] = *(const short8*)(W43f + ((size_t)(s * 2 + 0) * 64 + lane) * 8);
        wa[si][1] = *(const short8*)(W43f + ((size_t)(s * 2 + 1) * 64 + lane) * 8);
    }

    __syncthreads();

    float4v accB[4] = {};

    #pragma unroll
    for (int p = 0; p < 2; ++p) {
        // ---- stage A: wave wv handles local g-pairs gp2 = wv*2, wv*2+1 ----
        const int koff = 2 * p + (wv >> 2);
        const unsigned short* xrow = &xtile[(lr + koff) * CS + lh * 8];

        #pragma unroll
        for (int k2 = 0; k2 < 2; ++k2) {
            const int gp2 = wv * 2 + k2;          // local g-pair 0..15
            float4v accA[2][2];                   // [g parity q][oh]
            #pragma unroll
            for (int q = 0; q < 2; ++q) {
                const int gl = gp2 * 2 + q;       // local g 0..31
                const int g  = p * 32 + gl;
                short8 vfrag = *(const short8*)(xrow + (gl & 15) * 32);
                #pragma unroll
                for (int oh = 0; oh < 2; ++oh) {
                    short8 wfrag = *(const short8*)(W21f + ((size_t)(g * 2 + oh) * 64 + lane) * 8);
                    float4v z = {};
                    accA[q][oh] = __builtin_amdgcn_mfma_f32_16x16x32_bf16(vfrag, wfrag, z, 0, 0, 0);
                }
            }
            // pack across g: dword(m) = (bf16 g-even, bf16 g-odd); b128 write of 4 m
            #pragma unroll
            for (int oh = 0; oh < 2; ++oh) {
                const int a = oh * 16 + lr;
                uint4 w;
                w.x = bf16pk(accA[0][oh][0], accA[1][oh][0]);
                w.y = bf16pk(accA[0][oh][1], accA[1][oh][1]);
                w.z = bf16pk(accA[0][oh][2], accA[1][oh][2]);
                w.w = bf16pk(accA[0][oh][3], accA[1][oh][3]);
                *(uint4*)&out2[gp2 * GP2S + a * 16 + lh * 4] = w;
            }
        }
        __syncthreads();

        // ---- stage B: wave wv accumulates s = wv*4 .. +3 over this phase's 32 g ----
        #pragma unroll
        for (int si = 0; si < 4; ++si) {
            const int s = wv * 4 + si;
            const int rb = s * 16 + lr;
            uint4 uw;
            uw.x = out2[(lh * 4 + 0) * GP2S + rb];
            uw.y = out2[(lh * 4 + 1) * GP2S + rb];
            uw.z = out2[(lh * 4 + 2) * GP2S + rb];
            uw.w = out2[(lh * 4 + 3) * GP2S + rb];
            short8 bb = *reinterpret_cast<short8*>(&uw);
            accB[si] = __builtin_amdgcn_mfma_f32_16x16x32_bf16(wa[si][p], bb, accB[si], 0, 0, 0);
        }
        if (p == 0) __syncthreads();   // protect out2 before phase-1 overwrite
    }

    // ---- store (verified R10) ----
    const int lpos = l0 + lr;
    if (lpos < L_OUT) {
        #pragma unroll
        for (int si = 0; si < 4; ++si) {
            const int s = wv * 4 + si;
            #pragma unroll
            for (int i = 0; i < 4; ++i) {
                int o4 = s + 32 * (lh * 4 + i);
                out[((size_t)(b * 512 + o4)) * L_OUT + lpos] = accB[si][i] + bias[o4];
            }
        }
    }
}

// ---------------- fallback (round-1 kernel, used if ws too small) ----------------
__global__ __launch_bounds__(256)
void debut_fused_kernel(const float* __restrict__ x,
                        const float* __restrict__ tw,
                        const float* __restrict__ bias,
                        float* __restrict__ out)
{
    __shared__ float xt[C_IN * XT_PAD];
    __shared__ float bufA[2048];
    __shared__ float bufB[2048];
    const int tile = blockIdx.x, b = blockIdx.y;
    const int l0 = tile * 16;
    const int tid = threadIdx.x;
    const float* xb = x + (size_t)b * C_IN * L_IN;
    for (int idx = tid; idx < C_IN * 19; idx += 256) {
        int c = idx / 19, ll = idx - c * 19, l = l0 + ll;
        xt[c * XT_PAD + ll] = (l < L_IN) ? xb[c * L_IN + l] : 0.0f;
    }
    __syncthreads();
    const float* t1 = tw; const float* t2 = tw + 8192;
    const float* t3 = tw + 24576; const float* t4 = tw + 32768;
    for (int rr = 0; rr < 16; ++rr) {
        const int l = l0 + rr;
        if (l >= L_OUT) break;
        #pragma unroll
        for (int i = 0; i < 8; ++i) {
            int o = tid + 256 * i, gb = o >> 2, k = gb >> 7, cb = (gb & 127) << 2;
            const float4 tq = *reinterpret_cast<const float4*>(t1 + o * 4);
            const float* xp = &xt[cb * XT_PAD + rr + k];
            bufA[o] = tq.x * xp[0] + tq.y * xp[XT_PAD] + tq.z * xp[2 * XT_PAD] + tq.w * xp[3 * XT_PAD];
        }
        __syncthreads();
        #pragma unroll
        for (int i = 0; i < 8; ++i) {
            int o = tid + 256 * i, gb = o >> 5, r = (o >> 2) & 7, d = o & 3;
            const float* tp = t2 + (((gb << 2) + d) * 8 + r) * 8;
            const float* ip = &bufA[(gb << 5) + d];
            float acc = 0.0f;
            #pragma unroll
            for (int c = 0; c < 8; ++c) acc += tp[c] * ip[c << 2];
            bufB[o] = acc;
        }
        __syncthreads();
        #pragma unroll
        for (int i = 0; i < 4; ++i) {
            int o = tid + 256 * i, gb = o >> 7, r = (o >> 5) & 3, d = o & 31;
            const float* tp = t3 + (((gb << 5) + d) * 4 + r) * 8;
            const float* ip = &bufB[(gb << 8) + d];
            float acc = 0.0f;
            #pragma unroll
            for (int c = 0; c < 8; ++c) acc += tp[c] * ip[c << 5];
            bufA[o] = acc;
        }
        __syncthreads();
        #pragma unroll
        for (int i = 0; i < 2; ++i) {
            int o = tid + 256 * i, r = o >> 6, d = o & 63;
            const float* tp = t4 + ((d << 3) + r) * 16;
            float acc = 0.0f;
            #pragma unroll
            for (int c = 0; c < 16; ++c) acc += tp[c] * bufA[(c << 6) + d];
            out[((size_t)(b * 512 + o)) * L_OUT + l] = acc + bias[o];
        }
        __syncthreads();
    }
}

extern "C" void kernel_launch(void* const* d_in, const int* in_sizes, int n_in,
                              void* d_out, int out_size, void* d_ws, size_t ws_size,
                              hipStream_t stream) {
    const float* x    = (const float*)d_in[0];
    const float* tw   = (const float*)d_in[1];
    const float* bias = (const float*)d_in[2];
    float* out = (float*)d_out;

    const size_t W21_B = 65536 * 2;      // 128 KB
    const size_t W43_B = 32768 * 2;      // 64 KB

    if (ws_size < W21_B + W43_B) {
        dim3 grid(128, 16);
        debut_fused_kernel<<<grid, dim3(256), 0, stream>>>(x, tw, bias, out);
        return;
    }

    unsigned short* W21f = (unsigned short*)d_ws;
    unsigned short* W43f = (unsigned short*)((char*)d_ws + W21_B);

    build_wf<<<dim3(384), dim3(256), 0, stream>>>(tw, W21f, W43f);
    debut_fused_mfma<<<dim3(2048), dim3(512), 0, stream>>>(W21f, W43f, x, bias, out);
}

// Round 12
// 45.086 us; speedup vs baseline: 1.3979x; 1.0244x over previous
//
#include <hip/hip_runtime.h>

#define L_IN   2048
#define C_IN   512
#define L_OUT  2045
#define XT_PAD 21
#define CS     520    // xtile row stride (elems)
#define GP2S   524    // out2 g-pair stride (dwords)

typedef short short8 __attribute__((ext_vector_type(8)));
typedef float float4v __attribute__((ext_vector_type(4)));

__device__ __forceinline__ unsigned short bf16r(float f) {
    unsigned u = __float_as_uint(f);
    unsigned r = (u + 0x7FFFu + ((u >> 16) & 1u)) >> 16;
    return (unsigned short)r;
}

__device__ __forceinline__ unsigned bf16pk(float lo, float hi) {
    return (unsigned)bf16r(lo) | ((unsigned)bf16r(hi) << 16);
}

// ---------------- kernel 1: build W21/W43 in MFMA fragment layout (verified R3/R5/R6) ----
__global__ __launch_bounds__(256)
void build_wf(const float* __restrict__ tw, unsigned short* __restrict__ W21f,
              unsigned short* __restrict__ W43f) {
    int id = blockIdx.x * 256 + threadIdx.x;
    if (id < 65536) {
        int p = id & 7, lane = (id >> 3) & 63, oh = (id >> 9) & 1, g = id >> 10;
        int a = oh * 16 + (lane & 15);
        int e = ((lane >> 4) & 3) * 8 + p;
        int r2 = a >> 2, d2 = a & 3, c2 = e >> 2, c1 = e & 3;
        float v = tw[8192 + ((g * 4 + d2) * 8 + r2) * 8 + c2]
                * tw[(g * 8 + c2) * 16 + d2 * 4 + c1];
        W21f[id] = bf16r(v);
    } else if (id < 98304) {
        int id2 = id - 65536;
        int p = id2 & 7, lane = (id2 >> 3) & 63, kh = (id2 >> 9) & 1, s = id2 >> 10;
        int u = lane & 15;
        int w = kh * 32 + ((lane >> 4) & 3) * 8 + p;
        int r4 = u >> 1, hi = u & 1, d4 = hi * 32 + s, p2 = w >> 3, c3 = w & 7;
        float v = 0.f;
        #pragma unroll
        for (int lo = 0; lo < 2; ++lo)
            v += tw[32768 + (d4 * 8 + r4) * 16 + (2 * p2 + lo)]
               * tw[24576 + ((p2 * 32 + s) * 4 + (2 * lo + hi)) * 8 + c3];
        W43f[id2] = bf16r(v);
    }
}

// ---------------- kernel 2: fused two-stage block MFMA, register-prefetched weights ------
// Layouts identical to R11 (verified). Difference: all W21f/W43f global loads are issued
// BEFORE a barrier that precedes their use, so no phase ever waits on global memory.
__global__ __launch_bounds__(512, 4)
void debut_fused_mfma(const unsigned short* __restrict__ W21f,
                      const unsigned short* __restrict__ W43f,
                      const float* __restrict__ x,
                      const float* __restrict__ bias, float* __restrict__ out) {
    __shared__ unsigned short xtile[19 * CS];   // 19760 B
    __shared__ unsigned int   out2[16 * GP2S];  // 33536 B

    // XCD-aware bijective swizzle (2048 blocks, 8 XCDs, 256 each)
    const int bid = blockIdx.x;
    const int swz = (bid & 7) * 256 + (bid >> 3);
    const int lt = swz & 127, b = swz >> 7;
    const int l0 = lt * 16;
    const int t = threadIdx.x;
    const int lane = t & 63, wv = t >> 6;        // 8 waves
    const int lr = lane & 15, lh = lane >> 4;

    const float* xb = x + (size_t)b * C_IN * L_IN;

    // ---- prefetch phase-0 stage-A weights (g = 0..31 slice for this wave) + stage-B wa ----
    // Issued first: latency hides under x staging; barrier-1's vmcnt drain completes them.
    short8 wf[8];   // [k2*4 + q*2 + oh], local g = wv*4 + k2*2 + q
    #pragma unroll
    for (int k2 = 0; k2 < 2; ++k2)
        #pragma unroll
        for (int q = 0; q < 2; ++q)
            #pragma unroll
            for (int oh = 0; oh < 2; ++oh) {
                const int g = (wv * 2 + k2) * 2 + q;   // phase-0 global g
                wf[k2 * 4 + q * 2 + oh] =
                    *(const short8*)(W21f + ((size_t)(g * 2 + oh) * 64 + lane) * 8);
            }
    short8 wa[4][2];
    #pragma unroll
    for (int si = 0; si < 4; ++si) {
        int s = wv * 4 + si;
        wa[si][0] = *(const short8*)(W43f + ((size_t)(s * 2 + 0) * 64 + lane) * 8);
        wa[si][1] = *(const short8*)(W43f + ((size_t)(s * 2 + 1) * 64 + lane) * 8);
    }

    // ---- stage x: x[b, :, l0..l0+18] -> xtile (verified R10) ----
    {
        const int lq = t & 3;
        #pragma unroll
        for (int pass = 0; pass < 4; ++pass) {
            int cc = pass * 128 + (t >> 2);
            float4 v = *reinterpret_cast<const float4*>(xb + (size_t)cc * L_IN + l0 + lq * 4);
            int base = (lq * 4) * CS + cc;
            xtile[base         ] = bf16r(v.x);
            xtile[base + CS    ] = bf16r(v.y);
            xtile[base + 2 * CS] = bf16r(v.z);
            xtile[base + 3 * CS] = bf16r(v.w);
        }
        int cc = t;
        int lx = l0 + 16; if (lx > L_IN - 4) lx = L_IN - 4;
        float4 v = *reinterpret_cast<const float4*>(xb + (size_t)cc * L_IN + lx);
        int base = 16 * CS + cc;
        xtile[base         ] = bf16r(v.x);
        xtile[base + CS    ] = bf16r(v.y);
        xtile[base + 2 * CS] = bf16r(v.z);
    }

    __syncthreads();   // xtile ready; wf/wa loads drained

    float4v accB[4] = {};

    // =================== phase 0 ===================
    {
        const int koff = 0 + (wv >> 2);
        const unsigned short* xrow = &xtile[(lr + koff) * CS + lh * 8];
        #pragma unroll
        for (int k2 = 0; k2 < 2; ++k2) {
            const int gp2 = wv * 2 + k2;
            float4v accA[2][2];
            #pragma unroll
            for (int q = 0; q < 2; ++q) {
                const int gl = gp2 * 2 + q;
                short8 vfrag = *(const short8*)(xrow + (gl & 15) * 32);
                #pragma unroll
                for (int oh = 0; oh < 2; ++oh) {
                    float4v z = {};
                    accA[q][oh] = __builtin_amdgcn_mfma_f32_16x16x32_bf16(
                        vfrag, wf[k2 * 4 + q * 2 + oh], z, 0, 0, 0);
                }
            }
            #pragma unroll
            for (int oh = 0; oh < 2; ++oh) {
                const int a = oh * 16 + lr;
                uint4 w;
                w.x = bf16pk(accA[0][oh][0], accA[1][oh][0]);
                w.y = bf16pk(accA[0][oh][1], accA[1][oh][1]);
                w.z = bf16pk(accA[0][oh][2], accA[1][oh][2]);
                w.w = bf16pk(accA[0][oh][3], accA[1][oh][3]);
                *(uint4*)&out2[gp2 * GP2S + a * 16 + lh * 4] = w;
            }
        }
        __syncthreads();   // out2 phase-0 ready

        // issue phase-1 stage-A weight loads now; the next barrier drains them
        #pragma unroll
        for (int k2 = 0; k2 < 2; ++k2)
            #pragma unroll
            for (int q = 0; q < 2; ++q)
                #pragma unroll
                for (int oh = 0; oh < 2; ++oh) {
                    const int g = 32 + (wv * 2 + k2) * 2 + q;   // phase-1 global g
                    wf[k2 * 4 + q * 2 + oh] =
                        *(const short8*)(W21f + ((size_t)(g * 2 + oh) * 64 + lane) * 8);
                }

        // stage B phase 0
        #pragma unroll
        for (int si = 0; si < 4; ++si) {
            const int s = wv * 4 + si;
            const int rb = s * 16 + lr;
            uint4 uw;
            uw.x = out2[(lh * 4 + 0) * GP2S + rb];
            uw.y = out2[(lh * 4 + 1) * GP2S + rb];
            uw.z = out2[(lh * 4 + 2) * GP2S + rb];
            uw.w = out2[(lh * 4 + 3) * GP2S + rb];
            short8 bb = *reinterpret_cast<short8*>(&uw);
            accB[si] = __builtin_amdgcn_mfma_f32_16x16x32_bf16(wa[si][0], bb, accB[si], 0, 0, 0);
        }
        __syncthreads();   // stage-B reads done; wf phase-1 drained
    }

    // =================== phase 1 ===================
    {
        const int koff = 2 + (wv >> 2);
        const unsigned short* xrow = &xtile[(lr + koff) * CS + lh * 8];
        #pragma unroll
        for (int k2 = 0; k2 < 2; ++k2) {
            const int gp2 = wv * 2 + k2;
            float4v accA[2][2];
            #pragma unroll
            for (int q = 0; q < 2; ++q) {
                const int gl = gp2 * 2 + q;
                short8 vfrag = *(const short8*)(xrow + (gl & 15) * 32);
                #pragma unroll
                for (int oh = 0; oh < 2; ++oh) {
                    float4v z = {};
                    accA[q][oh] = __builtin_amdgcn_mfma_f32_16x16x32_bf16(
                        vfrag, wf[k2 * 4 + q * 2 + oh], z, 0, 0, 0);
                }
            }
            #pragma unroll
            for (int oh = 0; oh < 2; ++oh) {
                const int a = oh * 16 + lr;
                uint4 w;
                w.x = bf16pk(accA[0][oh][0], accA[1][oh][0]);
                w.y = bf16pk(accA[0][oh][1], accA[1][oh][1]);
                w.z = bf16pk(accA[0][oh][2], accA[1][oh][2]);
                w.w = bf16pk(accA[0][oh][3], accA[1][oh][3]);
                *(uint4*)&out2[gp2 * GP2S + a * 16 + lh * 4] = w;
            }
        }
        __syncthreads();

        #pragma unroll
        for (int si = 0; si < 4; ++si) {
            const int s = wv * 4 + si;
            const int rb = s * 16 + lr;
            uint4 uw;
            uw.x = out2[(lh * 4 + 0) * GP2S + rb];
            uw.y = out2[(lh * 4 + 1) * GP2S + rb];
            uw.z = out2[(lh * 4 + 2) * GP2S + rb];
            uw.w = out2[(lh * 4 + 3) * GP2S + rb];
            short8 bb = *reinterpret_cast<short8*>(&uw);
            accB[si] = __builtin_amdgcn_mfma_f32_16x16x32_bf16(wa[si][1], bb, accB[si], 0, 0, 0);
        }
    }

    // ---- store (verified R10) ----
    const int lpos = l0 + lr;
    if (lpos < L_OUT) {
        #pragma unroll
        for (int si = 0; si < 4; ++si) {
            const int s = wv * 4 + si;
            #pragma unroll
            for (int i = 0; i < 4; ++i) {
                int o4 = s + 32 * (lh * 4 + i);
                out[((size_t)(b * 512 + o4)) * L_OUT + lpos] = accB[si][i] + bias[o4];
            }
        }
    }
}

// ---------------- fallback (round-1 kernel, used if ws too small) ----------------
__global__ __launch_bounds__(256)
void debut_fused_kernel(const float* __restrict__ x,
                        const float* __restrict__ tw,
                        const float* __restrict__ bias,
                        float* __restrict__ out)
{
    __shared__ float xt[C_IN * XT_PAD];
    __shared__ float bufA[2048];
    __shared__ float bufB[2048];
    const int tile = blockIdx.x, b = blockIdx.y;
    const int l0 = tile * 16;
    const int tid = threadIdx.x;
    const float* xb = x + (size_t)b * C_IN * L_IN;
    for (int idx = tid; idx < C_IN * 19; idx += 256) {
        int c = idx / 19, ll = idx - c * 19, l = l0 + ll;
        xt[c * XT_PAD + ll] = (l < L_IN) ? xb[c * L_IN + l] : 0.0f;
    }
    __syncthreads();
    const float* t1 = tw; const float* t2 = tw + 8192;
    const float* t3 = tw + 24576; const float* t4 = tw + 32768;
    for (int rr = 0; rr < 16; ++rr) {
        const int l = l0 + rr;
        if (l >= L_OUT) break;
        #pragma unroll
        for (int i = 0; i < 8; ++i) {
            int o = tid + 256 * i, gb = o >> 2, k = gb >> 7, cb = (gb & 127) << 2;
            const float4 tq = *reinterpret_cast<const float4*>(t1 + o * 4);
            const float* xp = &xt[cb * XT_PAD + rr + k];
            bufA[o] = tq.x * xp[0] + tq.y * xp[XT_PAD] + tq.z * xp[2 * XT_PAD] + tq.w * xp[3 * XT_PAD];
        }
        __syncthreads();
        #pragma unroll
        for (int i = 0; i < 8; ++i) {
            int o = tid + 256 * i, gb = o >> 5, r = (o >> 2) & 7, d = o & 3;
            const float* tp = t2 + (((gb << 2) + d) * 8 + r) * 8;
            const float* ip = &bufA[(gb << 5) + d];
            float acc = 0.0f;
            #pragma unroll
            for (int c = 0; c < 8; ++c) acc += tp[c] * ip[c << 2];
            bufB[o] = acc;
        }
        __syncthreads();
        #pragma unroll
        for (int i = 0; i < 4; ++i) {
            int o = tid + 256 * i, gb = o >> 7, r = (o >> 5) & 3, d = o & 31;
            const float* tp = t3 + (((gb << 5) + d) * 4 + r) * 8;
            const float* ip = &bufB[(gb << 8) + d];
            float acc = 0.0f;
            #pragma unroll
            for (int c = 0; c < 8; ++c) acc += tp[c] * ip[c << 5];
            bufA[o] = acc;
        }
        __syncthreads();
        #pragma unroll
        for (int i = 0; i < 2; ++i) {
            int o = tid + 256 * i, r = o >> 6, d = o & 63;
            const float* tp = t4 + ((d << 3) + r) * 16;
            float acc = 0.0f;
            #pragma unroll
            for (int c = 0; c < 16; ++c) acc += tp[c] * bufA[(c << 6) + d];
            out[((size_t)(b * 512 + o)) * L_OUT + l] = acc + bias[o];
        }
        __syncthreads();
    }
}

extern "C" void kernel_launch(void* const* d_in, const int* in_sizes, int n_in,
                              void* d_out, int out_size, void* d_ws, size_t ws_size,
                              hipStream_t stream) {
    const float* x    = (const float*)d_in[0];
    const float* tw   = (const float*)d_in[1];
    const float* bias = (const float*)d_in[2];
    float* out = (float*)d_out;

    const size_t W21_B = 65536 * 2;      // 128 KB
    const size_t W43_B = 32768 * 2;      // 64 KB

    if (ws_size < W21_B + W43_B) {
        dim3 grid(128, 16);
        debut_fused_kernel<<<grid, dim3(256), 0, stream>>>(x, tw, bias, out);
        return;
    }

    unsigned short* W21f = (unsigned short*)d_ws;
    unsigned short* W43f = (unsigned short*)((char*)d_ws + W21_B);

    build_wf<<<dim3(384), dim3(256), 0, stream>>>(tw, W21f, W43f);
    debut_fused_mfma<<<dim3(2048), dim3(512), 0, stream>>>(W21f, W43f, x, bias, out);
}